// Round 13
// baseline (310.649 us; speedup 1.0000x reference)
//
#include <hip/hip_runtime.h>
#include <stdint.h>

#define M_TOT 8192
#define N_TOT 4096
#define K_TOT 4096
#define NTILE 64   // K-tiles of BK=64

typedef __attribute__((ext_vector_type(8))) short bf16x8;
typedef __attribute__((ext_vector_type(16))) float f32x16;
typedef __attribute__((ext_vector_type(2))) unsigned short u16x2;
typedef __attribute__((ext_vector_type(4))) unsigned short u16x4;

typedef const __attribute__((address_space(1))) void* gas1;
typedef __attribute__((address_space(3))) void* las3;

__device__ __forceinline__ unsigned short bf16_rne(float f) {
    union { float f; unsigned int u; } v; v.f = f;
    unsigned int u = v.u;
    return (unsigned short)((u + 0x7FFFu + ((u >> 16) & 1u)) >> 16);
}

// Exact collapse of the reference FP4(E2M1) quant-dequant on a = |w|/scale.
__device__ __forceinline__ float fp4_qdq(float wv, float scale) {
    float a = fabsf(wv) / scale;
    float q;
    if      (a <= 0.25f) q = 0.0f;
    else if (a <  1.0f ) q = 0.5f;
    else if (a <= 1.25f) q = 1.0f;
    else if (a <  2.0f ) q = 1.5f;
    else if (a <= 2.5f ) q = 2.0f;
    else if (a <  4.0f ) q = 3.0f;
    else if (a <= 5.0f ) q = 4.0f;
    else                 q = 6.0f;
    float d = q * scale;
    return wv < 0.0f ? -d : d;
}

// Fused prep: blocks [0,2048) convert x f32->bf16; blocks [2048,4096) quantize w.
// At HBM BW floor (288MB moved ~= 46us).
__global__ __launch_bounds__(256) void prep_kernel(const float* __restrict__ w,
                                                   unsigned short* __restrict__ wb,
                                                   const float* __restrict__ x,
                                                   unsigned short* __restrict__ xb) {
    if (blockIdx.x < 2048) {
        const int total4 = (M_TOT * K_TOT) / 4;
        int stride = 2048 * 256;
        for (int i = blockIdx.x * 256 + threadIdx.x; i < total4; i += stride) {
            float4 v = ((const float4*)x)[i];
            u16x4 o;
            o.x = bf16_rne(v.x); o.y = bf16_rne(v.y);
            o.z = bf16_rne(v.z); o.w = bf16_rne(v.w);
            ((u16x4*)xb)[i] = o;
        }
    } else {
        int wv0 = (blockIdx.x - 2048) * 4 + (threadIdx.x >> 6);
        int lane = threadIdx.x & 63;
        const int ngroups = (N_TOT * K_TOT) / 128;   // 131072
        for (int g = wv0; g < ngroups; g += 2048 * 4) {
            size_t base = (size_t)g * 128;
            float2 v = ((const float2*)(w + base))[lane];
            float mx = fmaxf(fabsf(v.x), fabsf(v.y));
            #pragma unroll
            for (int off = 32; off; off >>= 1) mx = fmaxf(mx, __shfl_xor(mx, off));
            float scale = fmaxf(mx / 6.0f, 1e-8f);
            u16x2 o;
            o.x = bf16_rne(fp4_qdq(v.x, scale));
            o.y = bf16_rne(fp4_qdq(v.y, scale));
            *(u16x2*)(wb + base + (size_t)lane * 2) = o;
        }
    }
}

// -- 256x256 GEMM, 32x32x16 MFMA, R12 sync skeleton, 32B-read-tuned layout --
// C[m][n] = sum_k A[m][k]*B[n][k] + bias[n]; A,B bf16 K-contig, C f32.
// 512 threads = 8 waves (2M x 4N); per-wave output 128x64 = 4x2 tiles of 32x32.
// LDS: A regions at [BB*32768 + KK*16384], B at +65536. Region (16KB) layout
// [ks:2][row:256][chunk:2]x16B; chunk c of row r holds logical k-half
// c ^ ((r>>2)&1)  -> each 16-lane ds_read_b128 group hits every bank-quad
// exactly 2x (2-way = free). Staging: thread t owns row t>>1, chunk t&1,
// src col ((t&1)^((t>>3)&1))*8 elems; 2x16B loads (ks0 -> t*16, ks1 ->
// 8192+t*16), wave-uniform base + lane*16 preserved.
// Sync structure (1 barrier/phase, vm8@ph3, vm6@ph4, preloads) = R12 verified.

#define BAR()      __builtin_amdgcn_s_barrier()
#define SCHEDB()   __builtin_amdgcn_sched_barrier(0)
#define WAITVM8()  asm volatile("s_waitcnt vmcnt(8)" ::: "memory")
#define WAITVM6()  asm volatile("s_waitcnt vmcnt(6)" ::: "memory")
#define WAITVM0()  asm volatile("s_waitcnt vmcnt(0)" ::: "memory")

__global__ __launch_bounds__(512) void gemm_kernel(const unsigned short* __restrict__ A,
                                                   const unsigned short* __restrict__ B,
                                                   const float* __restrict__ bias,
                                                   float* __restrict__ C) {
    extern __shared__ unsigned char lds[];   // 131072 bytes

    // 2D-chunked XCD swizzle: XCD = bid&7 owns a 16tm x 4tn rectangle;
    // its 32 concurrently-resident blocks cover 8tm x 4tn -> L2 set ~384KB.
    const int bid = blockIdx.x;
    const int xcd = bid & 7;
    const int idx = bid >> 3;          // 0..63
    const int tm = ((xcd >> 2) << 4) + (idx >> 2);   // 0..31
    const int tn = ((xcd & 3) << 2) + (idx & 3);     // 0..15
    const int m0 = tm << 8, n0 = tn << 8;

    const int t = threadIdx.x;
    const int l = t & 63;
    const int wid = t >> 6;
    const int wr = wid >> 2;   // 0..1
    const int wc = wid & 3;    // 0..3
    const int l31 = l & 31;
    const int h32 = l >> 5;

    // Read bases: chunk select c = h32 ^ ((l31>>2)&1) (row upper bits even).
    const unsigned cread = (unsigned)(h32 ^ ((l31 >> 2) & 1));
    unsigned offA[4];   // [mi] -> + ks*8192 at use
    #pragma unroll
    for (int mi = 0; mi < 4; ++mi)
        offA[mi] = (unsigned)(wr * 128 + mi * 32 + l31) * 32u + cread * 16u;
    unsigned offB[2];   // [nj], B matrix base +65536 baked in
    #pragma unroll
    for (int nj = 0; nj < 2; ++nj)
        offB[nj] = 65536u + (unsigned)(wc * 64 + nj * 32 + l31) * 32u + cread * 16u;

    // Staging: thread t owns row t>>1, chunk t&1; src col ((t&1)^((t>>3)&1))*8.
    const int sr = t >> 1;
    const int scol = ((t & 1) ^ ((t >> 3) & 1)) * 8;
    const unsigned short* arow = A + (size_t)(m0 + sr) * K_TOT + scol;
    const unsigned short* brow = B + (size_t)(n0 + sr) * K_TOT + scol;
    const unsigned lo0 = (unsigned)t * 16u;          // ks=0 granule
    const unsigned lo1 = lo0 + 8192u;                // ks=1 granule

// Region base: MAT(A=0,B=65536) + BB*32768 + KK*16384. Two 16B loads:
// ks0 (k-offset +0) -> lo0 ; ks1 (+16 elems) -> lo1.
#define STAGE(ROWP, MATOFF, KK, TT, BB) do {                                         \
      const unsigned _base = (MATOFF) + (unsigned)(BB) * 32768u + (KK) * 16384u;     \
      const int _ko = (TT) * 64 + (KK) * 32;                                         \
      __builtin_amdgcn_global_load_lds((gas1)(ROWP + _ko), (las3)(lds + _base + lo0), 16, 0, 0); \
      __builtin_amdgcn_global_load_lds((gas1)(ROWP + _ko + 16), (las3)(lds + _base + lo1), 16, 0, 0); \
    } while (0)
#define STAGE_A(KK, TT, BB) STAGE(arow, 0u, KK, TT, BB)
#define STAGE_B(KK, TT, BB) STAGE(brow, 65536u, KK, TT, BB)

// A-frags for m-half MIH: DST[i2*2+ks] = frag(mi=MIH*2+i2, ks).
#define LOAD_A4(DST, MIH, KK, BB) do {                                               \
      _Pragma("unroll")                                                              \
      for (int i2 = 0; i2 < 2; ++i2)                                                 \
        _Pragma("unroll")                                                            \
        for (int ks = 0; ks < 2; ++ks)                                               \
          DST[i2 * 2 + ks] = *(const bf16x8*)(lds + ((BB) * 32768u + (KK) * 16384u   \
                               + (unsigned)ks * 8192u) + offA[(MIH) * 2 + i2]);      \
    } while (0)

// B-frags: DST[nj*2+ks].
#define LOAD_B4(DST, KK, BB) do {                                                    \
      _Pragma("unroll")                                                              \
      for (int nj = 0; nj < 2; ++nj)                                                 \
        _Pragma("unroll")                                                            \
        for (int ks = 0; ks < 2; ++ks)                                               \
          DST[nj * 2 + ks] = *(const bf16x8*)(lds + ((BB) * 32768u + (KK) * 16384u   \
                               + (unsigned)ks * 8192u) + offB[nj]);                  \
    } while (0)

// 8 MFMA 32x32x16 per phase: m-half MIH, both nj, both ks.
#define MFMA8(MIH, AF, BG) do {                                                      \
      _Pragma("unroll")                                                              \
      for (int i2 = 0; i2 < 2; ++i2)                                                 \
        _Pragma("unroll")                                                            \
        for (int nj = 0; nj < 2; ++nj)                                               \
          _Pragma("unroll")                                                          \
          for (int ks = 0; ks < 2; ++ks)                                             \
            acc[((MIH) * 2 + i2) * 2 + nj] = __builtin_amdgcn_mfma_f32_32x32x16_bf16( \
                AF[i2 * 2 + ks], BG[nj * 2 + ks], acc[((MIH) * 2 + i2) * 2 + nj],    \
                0, 0, 0);                                                            \
    } while (0)

// One K-tile = 4 phases, ONE barrier each; reads under prior MFMA (R12).
#define KTILE(U, BB) do {                                                            \
      const int tt1 = ((U) + 1 < NTILE) ? (U) + 1 : (U) - 1;                         \
      const int tt2 = ((U) + 2 < NTILE) ? (U) + 2 : (U);                             \
      /* phase 1: KK=0 m-half 0 */                                                   \
      STAGE_A(1, tt1, 1 - (BB));                                                     \
      __builtin_amdgcn_s_setprio(1); MFMA8(0, af0, bgA);                             \
      __builtin_amdgcn_s_setprio(0);                                                 \
      LOAD_A4(af1, 1, 0, BB);                                                        \
      BAR(); SCHEDB();                                                               \
      /* phase 2: KK=0 m-half 1 */                                                   \
      STAGE_B(0, tt2, BB);                                                           \
      __builtin_amdgcn_s_setprio(1); MFMA8(1, af1, bgA);                             \
      __builtin_amdgcn_s_setprio(0);                                                 \
      LOAD_B4(bgB, 1, BB); LOAD_A4(af0, 0, 1, BB);                                   \
      BAR(); SCHEDB();                                                               \
      /* phase 3: KK=1 m-half 0 */                                                   \
      STAGE_A(0, tt2, BB);                                                           \
      __builtin_amdgcn_s_setprio(1); MFMA8(0, af0, bgB);                             \
      __builtin_amdgcn_s_setprio(0);                                                 \
      LOAD_A4(af1, 1, 1, BB);                                                        \
      WAITVM8(); SCHEDB(); BAR(); SCHEDB();                                          \
      /* phase 4: KK=1 m-half 1 */                                                   \
      STAGE_B(1, tt2, BB);                                                           \
      __builtin_amdgcn_s_setprio(1); MFMA8(1, af1, bgB);                             \
      __builtin_amdgcn_s_setprio(0);                                                 \
      LOAD_B4(bgA, 0, 1 - (BB)); LOAD_A4(af0, 0, 0, 1 - (BB));                       \
      WAITVM6(); SCHEDB(); BAR(); SCHEDB();                                          \
    } while (0)

    f32x16 acc[8];
    #pragma unroll
    for (int i = 0; i < 8; ++i) acc[i] = (f32x16)0.0f;
    bf16x8 af0[4], af1[4], bgA[4], bgB[4];

    // Prologue: tile0 {Ak0,Bk0,Ak1,Bk1}->buf0, tile1 {Ak0,Bk0,Bk1}->buf1;
    // 14 issued, need first 8 (tile 0) -> vmcnt(6). Then preload ph1(0) frags.
    STAGE_A(0, 0, 0); STAGE_B(0, 0, 0); STAGE_A(1, 0, 0); STAGE_B(1, 0, 0);
    STAGE_A(0, 1, 1); STAGE_B(0, 1, 1); STAGE_B(1, 1, 1);
    WAITVM6(); SCHEDB();
    BAR(); SCHEDB();
    LOAD_B4(bgA, 0, 0); LOAD_A4(af0, 0, 0, 0);

    #pragma unroll 1
    for (int u = 0; u < NTILE; u += 2) {
        KTILE(u, 0);
        KTILE(u + 1, 1);
    }
    WAITVM0();   // drain idempotent tail reloads before LDS dealloc

    // Epilogue: 32x32 C/D layout col=lane&31, row=(reg&3)+8*(reg>>2)+4*(lane>>5)
    #pragma unroll
    for (int mi = 0; mi < 4; ++mi)
        #pragma unroll
        for (int nj = 0; nj < 2; ++nj) {
            int n = n0 + wc * 64 + nj * 32 + l31;
            float bv = bias[n];
            int mbase = m0 + wr * 128 + mi * 32 + 4 * h32;
            #pragma unroll
            for (int reg = 0; reg < 16; ++reg) {
                int row = mbase + (reg & 3) + 8 * (reg >> 2);
                C[(size_t)row * N_TOT + n] = acc[mi * 2 + nj][reg] + bv;
            }
        }
}

extern "C" void kernel_launch(void* const* d_in, const int* in_sizes, int n_in,
                              void* d_out, int out_size, void* d_ws, size_t ws_size,
                              hipStream_t stream) {
    const float* x    = (const float*)d_in[0];
    const float* w    = (const float*)d_in[1];
    const float* bias = (const float*)d_in[2];
    float* out = (float*)d_out;

    unsigned short* wb = (unsigned short*)d_ws;                      // 32 MiB
    unsigned short* xb = wb + (size_t)N_TOT * K_TOT;                 // +64 MiB

    prep_kernel<<<4096, 256, 0, stream>>>(w, wb, x, xb);

    hipFuncSetAttribute(reinterpret_cast<const void*>(gemm_kernel),
                        hipFuncAttributeMaxDynamicSharedMemorySize, 131072);
    gemm_kernel<<<512, 512, 131072, stream>>>(xb, wb, bias, out);
}

// Round 14
// 285.666 us; speedup vs baseline: 1.0875x; 1.0875x over previous
//
#include <hip/hip_runtime.h>
#include <stdint.h>

#define M_TOT 8192
#define N_TOT 4096
#define K_TOT 4096
#define NTILE 64   // K-tiles of BK=64

typedef __attribute__((ext_vector_type(8))) short bf16x8;
typedef __attribute__((ext_vector_type(4))) float f32x4;
typedef __attribute__((ext_vector_type(2))) unsigned short u16x2;
typedef __attribute__((ext_vector_type(4))) unsigned short u16x4;

typedef const __attribute__((address_space(1))) void* gas1;
typedef __attribute__((address_space(3))) void* las3;

__device__ __forceinline__ unsigned short bf16_rne(float f) {
    union { float f; unsigned int u; } v; v.f = f;
    unsigned int u = v.u;
    return (unsigned short)((u + 0x7FFFu + ((u >> 16) & 1u)) >> 16);
}

// Exact collapse of the reference FP4(E2M1) quant-dequant on a = |w|/scale.
__device__ __forceinline__ float fp4_qdq(float wv, float scale) {
    float a = fabsf(wv) / scale;
    float q;
    if      (a <= 0.25f) q = 0.0f;
    else if (a <  1.0f ) q = 0.5f;
    else if (a <= 1.25f) q = 1.0f;
    else if (a <  2.0f ) q = 1.5f;
    else if (a <= 2.5f ) q = 2.0f;
    else if (a <  4.0f ) q = 3.0f;
    else if (a <= 5.0f ) q = 4.0f;
    else                 q = 6.0f;
    float d = q * scale;
    return wv < 0.0f ? -d : d;
}

// Fused prep: blocks [0,2048) convert x f32->bf16; blocks [2048,4096) quantize w.
// At HBM BW floor (288MB moved ~= 46us).
__global__ __launch_bounds__(256) void prep_kernel(const float* __restrict__ w,
                                                   unsigned short* __restrict__ wb,
                                                   const float* __restrict__ x,
                                                   unsigned short* __restrict__ xb) {
    if (blockIdx.x < 2048) {
        const int total4 = (M_TOT * K_TOT) / 4;
        int stride = 2048 * 256;
        for (int i = blockIdx.x * 256 + threadIdx.x; i < total4; i += stride) {
            float4 v = ((const float4*)x)[i];
            u16x4 o;
            o.x = bf16_rne(v.x); o.y = bf16_rne(v.y);
            o.z = bf16_rne(v.z); o.w = bf16_rne(v.w);
            ((u16x4*)xb)[i] = o;
        }
    } else {
        int wv0 = (blockIdx.x - 2048) * 4 + (threadIdx.x >> 6);
        int lane = threadIdx.x & 63;
        const int ngroups = (N_TOT * K_TOT) / 128;   // 131072
        for (int g = wv0; g < ngroups; g += 2048 * 4) {
            size_t base = (size_t)g * 128;
            float2 v = ((const float2*)(w + base))[lane];
            float mx = fmaxf(fabsf(v.x), fabsf(v.y));
            #pragma unroll
            for (int off = 32; off; off >>= 1) mx = fmaxf(mx, __shfl_xor(mx, off));
            float scale = fmaxf(mx / 6.0f, 1e-8f);
            u16x2 o;
            o.x = bf16_rne(fp4_qdq(v.x, scale));
            o.y = bf16_rne(fp4_qdq(v.y, scale));
            *(u16x2*)(wb + base + (size_t)lane * 2) = o;
        }
    }
}

// ---- 256x256 GEMM, 1 barrier/phase, ZERO exposed ds_reads (R12, verified) ----
// C[m][n] = sum_k A[m][k]*B[n][k] + bias[n]; A,B bf16 K-contig, C f32.
// 512 threads = 8 waves (2M x 4N). BK=64 split into k-halves of 32.
// LDS: A regions at [BB*32768 + KK*16384], B at +65536; [256 rows][32 cols]
// bf16, rotation swizzle (pos p holds src granule (p-(r>>1))&3).
//
// vmcnt(8) before end-ph3 BAR publishes Bk0(u+1)/Ak0(u+1) (the 4 oldest of 12
// possibly-in-flight loads) -> ph1(u+1)'s reads (bgA, af0-q0) sit in ph4(u)'s
// post-MFMA slot. Every phase's operands preloaded under a prior MFMA section.
// End-ph4 vmcnt(6): in-flight {Bk1(u+1),Ak1(u+1),Bk0(u+2),Ak0(u+2),Bk1(u+2)}
// = 10 -> completes Bk1(u+1),Ak1(u+1), needed by ph2/ph3(u+1). OK
// Overwrite: early-read frags drain at ph1(u+1) MFMA (lgkm), >=1 BAR before
// their overwriting stages ph2(u+1)/ph3(u+1). Last tile's early reads: dead.

#define BAR()      __builtin_amdgcn_s_barrier()
#define SCHEDB()   __builtin_amdgcn_sched_barrier(0)
#define WAITVM8()  asm volatile("s_waitcnt vmcnt(8)" ::: "memory")
#define WAITVM6()  asm volatile("s_waitcnt vmcnt(6)" ::: "memory")
#define WAITVM0()  asm volatile("s_waitcnt vmcnt(0)" ::: "memory")

__global__ __launch_bounds__(512) void gemm_kernel(const unsigned short* __restrict__ A,
                                                   const unsigned short* __restrict__ B,
                                                   const float* __restrict__ bias,
                                                   float* __restrict__ C) {
    extern __shared__ unsigned char lds[];   // 131072 bytes

    // 2D-chunked XCD swizzle: XCD = bid&7 owns a 16tm x 4tn rectangle;
    // its 32 concurrently-resident blocks cover 8tm x 4tn -> L2 set ~384KB.
    const int bid = blockIdx.x;
    const int xcd = bid & 7;
    const int idx = bid >> 3;          // 0..63
    const int tm = ((xcd >> 2) << 4) + (idx >> 2);   // 0..31
    const int tn = ((xcd & 3) << 2) + (idx & 3);     // 0..15
    const int m0 = tm << 8, n0 = tn << 8;

    const int t = threadIdx.x;
    const int l = t & 63;
    const int wid = t >> 6;
    const int wr = wid >> 2;   // 0..1
    const int wc = wid & 3;    // 0..3
    const int l15 = l & 15;
    const int q4 = l >> 4;

    // Precomputed LDS read bases (rotation swizzle baked in).
    unsigned offA[8];   // [QM*4+i]
    #pragma unroll
    for (int QM = 0; QM < 2; ++QM)
        #pragma unroll
        for (int i = 0; i < 4; ++i) {
            int ra = wr * 128 + QM * 64 + i * 16 + l15;
            unsigned pa = (unsigned)((q4 + (ra >> 1)) & 3);
            offA[QM * 4 + i] = (unsigned)ra * 64u + pa * 16u;
        }
    unsigned offB[4];   // [n], B matrix base +65536 baked in
    #pragma unroll
    for (int n = 0; n < 4; ++n) {
        int rb = wc * 64 + n * 16 + l15;
        unsigned pb = (unsigned)((q4 + (rb >> 1)) & 3);
        offB[n] = 65536u + (unsigned)rb * 64u + pb * 16u;
    }

    // Staging: thread t covers granules G0=t, G1=512+t of each 1024-granule region.
    const int r0g = t >> 2,        p0g = t & 3;
    const int r1g = (512 + t) >> 2, p1g = t & 3;
    const int s0g = (p0g - (r0g >> 1)) & 3;
    const int s1g = (p1g - (r1g >> 1)) & 3;
    const unsigned short* arow0 = A + (size_t)(m0 + r0g) * K_TOT + s0g * 8;
    const unsigned short* arow1 = A + (size_t)(m0 + r1g) * K_TOT + s1g * 8;
    const unsigned short* brow0 = B + (size_t)(n0 + r0g) * K_TOT + s0g * 8;
    const unsigned short* brow1 = B + (size_t)(n0 + r1g) * K_TOT + s1g * 8;
    const unsigned lo0 = (unsigned)t * 16u;
    const unsigned lo1 = lo0 + 8192u;

// Region base: MAT(A=0,B=65536) + BB*32768 + KK*16384.
#define STAGE(ROW0, ROW1, MATOFF, KK, TT, BB) do {                                   \
      const unsigned _base = (MATOFF) + (unsigned)(BB) * 32768u + (KK) * 16384u;     \
      const int _ko = (TT) * 64 + (KK) * 32;                                         \
      __builtin_amdgcn_global_load_lds((gas1)(ROW0 + _ko), (las3)(lds + _base + lo0), 16, 0, 0); \
      __builtin_amdgcn_global_load_lds((gas1)(ROW1 + _ko), (las3)(lds + _base + lo1), 16, 0, 0); \
    } while (0)
#define STAGE_A(KK, TT, BB) STAGE(arow0, arow1, 0u, KK, TT, BB)
#define STAGE_B(KK, TT, BB) STAGE(brow0, brow1, 65536u, KK, TT, BB)

#define LOAD_A4(DST, QM, KK, BB) do {                                                \
      _Pragma("unroll")                                                              \
      for (int i = 0; i < 4; ++i)                                                    \
        DST[i] = *(const bf16x8*)(lds + ((BB) * 32768u + (KK) * 16384u)              \
                                  + offA[(QM) * 4 + i]);                             \
    } while (0)

#define LOAD_B4(DST, KK, BB) do {                                                    \
      _Pragma("unroll")                                                              \
      for (int n = 0; n < 4; ++n)                                                    \
        DST[n] = *(const bf16x8*)(lds + ((BB) * 32768u + (KK) * 16384u) + offB[n]);  \
    } while (0)

#define MFMA16(QM, AF, BG) do {                                                      \
      _Pragma("unroll")                                                              \
      for (int i = 0; i < 4; ++i)                                                    \
        _Pragma("unroll")                                                            \
        for (int n = 0; n < 4; ++n)                                                  \
          acc[(QM) * 4 + i][n] = __builtin_amdgcn_mfma_f32_16x16x32_bf16(            \
              AF[i], BG[n], acc[(QM) * 4 + i][n], 0, 0, 0);                          \
    } while (0)

// One K-tile = 4 phases, ONE barrier each. All reads under prior MFMA:
//  ph1 MFMA(af0,bgA) [preloaded ph4(u-1)]; post: af1(kk0).
//  ph2 MFMA(af1,bgA); post: bgB, af0(kk1).
//  ph3 MFMA(af0,bgB); post: af1(kk1); vmcnt(8) publishes u+1 kk0 regions.
//  ph4 MFMA(af1,bgB); post: bgA(u+1), af0-q0(u+1) from buf^1; vmcnt(6).
#define KTILE(U, BB) do {                                                            \
      const int tt1 = ((U) + 1 < NTILE) ? (U) + 1 : (U) - 1;                         \
      const int tt2 = ((U) + 2 < NTILE) ? (U) + 2 : (U);                             \
      /* phase 1: kk=0 qm=0 */                                                       \
      STAGE_A(1, tt1, 1 - (BB));                                                     \
      __builtin_amdgcn_s_setprio(1); MFMA16(0, af0, bgA);                            \
      __builtin_amdgcn_s_setprio(0);                                                 \
      LOAD_A4(af1, 1, 0, BB);                                                        \
      BAR(); SCHEDB();                                                               \
      /* phase 2: kk=0 qm=1 */                                                       \
      STAGE_B(0, tt2, BB);                                                           \
      __builtin_amdgcn_s_setprio(1); MFMA16(1, af1, bgA);                            \
      __builtin_amdgcn_s_setprio(0);                                                 \
      LOAD_B4(bgB, 1, BB); LOAD_A4(af0, 0, 1, BB);                                   \
      BAR(); SCHEDB();                                                               \
      /* phase 3: kk=1 qm=0 */                                                       \
      STAGE_A(0, tt2, BB);                                                           \
      __builtin_amdgcn_s_setprio(1); MFMA16(0, af0, bgB);                            \
      __builtin_amdgcn_s_setprio(0);                                                 \
      LOAD_A4(af1, 1, 1, BB);                                                        \
      WAITVM8(); SCHEDB(); BAR(); SCHEDB();                                          \
      /* phase 4: kk=1 qm=1 */                                                       \
      STAGE_B(1, tt2, BB);                                                           \
      __builtin_amdgcn_s_setprio(1); MFMA16(1, af1, bgB);                            \
      __builtin_amdgcn_s_setprio(0);                                                 \
      LOAD_B4(bgA, 0, 1 - (BB)); LOAD_A4(af0, 0, 0, 1 - (BB));                       \
      WAITVM6(); SCHEDB(); BAR(); SCHEDB();                                          \
    } while (0)

    f32x4 acc[8][4];
    #pragma unroll
    for (int i = 0; i < 8; ++i)
        #pragma unroll
        for (int j = 0; j < 4; ++j)
            acc[i][j] = (f32x4)0.0f;
    bf16x8 af0[4], af1[4], bgA[4], bgB[4];

    // Prologue: tile0 {Ak0,Bk0,Ak1,Bk1}->buf0, tile1 {Ak0,Bk0,Bk1}->buf1;
    // 14 issued, need first 8 (tile 0) -> vmcnt(6). Then preload ph1(0) frags.
    STAGE_A(0, 0, 0); STAGE_B(0, 0, 0); STAGE_A(1, 0, 0); STAGE_B(1, 0, 0);
    STAGE_A(0, 1, 1); STAGE_B(0, 1, 1); STAGE_B(1, 1, 1);
    WAITVM6(); SCHEDB();
    BAR(); SCHEDB();
    LOAD_B4(bgA, 0, 0); LOAD_A4(af0, 0, 0, 0);

    #pragma unroll 1
    for (int u = 0; u < NTILE; u += 2) {
        KTILE(u, 0);
        KTILE(u + 1, 1);
    }
    WAITVM0();   // drain idempotent tail reloads before LDS dealloc

    // Epilogue: C/D layout col=lane&15, row=(lane>>4)*4+reg
    #pragma unroll
    for (int j = 0; j < 4; ++j) {
        int n = n0 + wc * 64 + j * 16 + l15;
        float bv = bias[n];
        #pragma unroll
        for (int i = 0; i < 8; ++i) {
            int mb = m0 + wr * 128 + i * 16 + (q4 << 2);
            #pragma unroll
            for (int r = 0; r < 4; ++r)
                C[(size_t)(mb + r) * N_TOT + n] = acc[i][j][r] + bv;
        }
    }
}

extern "C" void kernel_launch(void* const* d_in, const int* in_sizes, int n_in,
                              void* d_out, int out_size, void* d_ws, size_t ws_size,
                              hipStream_t stream) {
    const float* x    = (const float*)d_in[0];
    const float* w    = (const float*)d_in[1];
    const float* bias = (const float*)d_in[2];
    float* out = (float*)d_out;

    unsigned short* wb = (unsigned short*)d_ws;                      // 32 MiB
    unsigned short* xb = wb + (size_t)N_TOT * K_TOT;                 // +64 MiB

    prep_kernel<<<4096, 256, 0, stream>>>(w, wb, x, xb);

    hipFuncSetAttribute(reinterpret_cast<const void*>(gemm_kernel),
                        hipFuncAttributeMaxDynamicSharedMemorySize, 131072);
    gemm_kernel<<<512, 512, 131072, stream>>>(xb, wb, bias, out);
}

// Round 15
// 285.222 us; speedup vs baseline: 1.0891x; 1.0016x over previous
//
#include <hip/hip_runtime.h>
#include <stdint.h>

#define M_TOT 8192
#define N_TOT 4096
#define K_TOT 4096
#define NTILE 64   // K-tiles of BK=64

typedef __attribute__((ext_vector_type(8))) short bf16x8;
typedef __attribute__((ext_vector_type(4))) float f32x4;
typedef __attribute__((ext_vector_type(2))) unsigned short u16x2;
typedef __attribute__((ext_vector_type(4))) unsigned short u16x4;

typedef const __attribute__((address_space(1))) void* gas1;
typedef __attribute__((address_space(3))) void* las3;

__device__ __forceinline__ unsigned short bf16_rne(float f) {
    union { float f; unsigned int u; } v; v.f = f;
    unsigned int u = v.u;
    return (unsigned short)((u + 0x7FFFu + ((u >> 16) & 1u)) >> 16);
}

// Exact collapse of the reference FP4(E2M1) quant-dequant on a = |w|/scale.
__device__ __forceinline__ float fp4_qdq(float wv, float scale) {
    float a = fabsf(wv) / scale;
    float q;
    if      (a <= 0.25f) q = 0.0f;
    else if (a <  1.0f ) q = 0.5f;
    else if (a <= 1.25f) q = 1.0f;
    else if (a <  2.0f ) q = 1.5f;
    else if (a <= 2.5f ) q = 2.0f;
    else if (a <  4.0f ) q = 3.0f;
    else if (a <= 5.0f ) q = 4.0f;
    else                 q = 6.0f;
    float d = q * scale;
    return wv < 0.0f ? -d : d;
}

// Fused prep: blocks [0,2048) convert x f32->bf16; blocks [2048,4096) quantize w.
// At HBM BW floor (288MB moved ~= 46us).
__global__ __launch_bounds__(256) void prep_kernel(const float* __restrict__ w,
                                                   unsigned short* __restrict__ wb,
                                                   const float* __restrict__ x,
                                                   unsigned short* __restrict__ xb) {
    if (blockIdx.x < 2048) {
        const int total4 = (M_TOT * K_TOT) / 4;
        int stride = 2048 * 256;
        for (int i = blockIdx.x * 256 + threadIdx.x; i < total4; i += stride) {
            float4 v = ((const float4*)x)[i];
            u16x4 o;
            o.x = bf16_rne(v.x); o.y = bf16_rne(v.y);
            o.z = bf16_rne(v.z); o.w = bf16_rne(v.w);
            ((u16x4*)xb)[i] = o;
        }
    } else {
        int wv0 = (blockIdx.x - 2048) * 4 + (threadIdx.x >> 6);
        int lane = threadIdx.x & 63;
        const int ngroups = (N_TOT * K_TOT) / 128;   // 131072
        for (int g = wv0; g < ngroups; g += 2048 * 4) {
            size_t base = (size_t)g * 128;
            float2 v = ((const float2*)(w + base))[lane];
            float mx = fmaxf(fabsf(v.x), fabsf(v.y));
            #pragma unroll
            for (int off = 32; off; off >>= 1) mx = fmaxf(mx, __shfl_xor(mx, off));
            float scale = fmaxf(mx / 6.0f, 1e-8f);
            u16x2 o;
            o.x = bf16_rne(fp4_qdq(v.x, scale));
            o.y = bf16_rne(fp4_qdq(v.y, scale));
            *(u16x2*)(wb + base + (size_t)lane * 2) = o;
        }
    }
}

// ---- 256x256 GEMM: R12 main loop (verified) + LDS-transposed epilogue ----
// C[m][n] = sum_k A[m][k]*B[n][k] + bias[n]; A,B bf16 K-contig, C f32.
// 512 threads = 8 waves (2M x 4N). BK=64 split into k-halves of 32.
// LDS (main loop): A regions at [BB*32768 + KK*16384], B at +65536; [256][32]
// bf16, rotation swizzle (pos p holds src granule (p-(r>>1))&3).
// Sync: 1 barrier/phase, all ds_reads under prior MFMA, vmcnt(8)@ph3,
// vmcnt(6)@ph4 (R12-verified ledger; see KTILE comments).
// Epilogue: after WAITVM0+BAR the LDS is dead -> stage each 128-row half as
// f32 [128][258] (stride-258: write pattern is 2-way bank = free), then all
// threads read 16B/lane contiguous and store dwordx4 (1KB/wave-instr, fully
// coalesced) instead of 128 scalar dword stores at 64B-segment efficiency.

#define BAR()      __builtin_amdgcn_s_barrier()
#define SCHEDB()   __builtin_amdgcn_sched_barrier(0)
#define WAITVM8()  asm volatile("s_waitcnt vmcnt(8)" ::: "memory")
#define WAITVM6()  asm volatile("s_waitcnt vmcnt(6)" ::: "memory")
#define WAITVM0()  asm volatile("s_waitcnt vmcnt(0)" ::: "memory")

#define EPI_STRIDE 258   // f32 stride; 128*258*4 = 132096 B LDS

__global__ __launch_bounds__(512) void gemm_kernel(const unsigned short* __restrict__ A,
                                                   const unsigned short* __restrict__ B,
                                                   const float* __restrict__ bias,
                                                   float* __restrict__ C) {
    extern __shared__ unsigned char lds[];   // 135168 bytes

    // 2D-chunked XCD swizzle: XCD = bid&7 owns a 16tm x 4tn rectangle;
    // its 32 concurrently-resident blocks cover 8tm x 4tn -> L2 set ~384KB.
    const int bid = blockIdx.x;
    const int xcd = bid & 7;
    const int idx = bid >> 3;          // 0..63
    const int tm = ((xcd >> 2) << 4) + (idx >> 2);   // 0..31
    const int tn = ((xcd & 3) << 2) + (idx & 3);     // 0..15
    const int m0 = tm << 8, n0 = tn << 8;

    const int t = threadIdx.x;
    const int l = t & 63;
    const int wid = t >> 6;
    const int wr = wid >> 2;   // 0..1
    const int wc = wid & 3;    // 0..3
    const int l15 = l & 15;
    const int q4 = l >> 4;

    // Precomputed LDS read bases (rotation swizzle baked in).
    unsigned offA[8];   // [QM*4+i]
    #pragma unroll
    for (int QM = 0; QM < 2; ++QM)
        #pragma unroll
        for (int i = 0; i < 4; ++i) {
            int ra = wr * 128 + QM * 64 + i * 16 + l15;
            unsigned pa = (unsigned)((q4 + (ra >> 1)) & 3);
            offA[QM * 4 + i] = (unsigned)ra * 64u + pa * 16u;
        }
    unsigned offB[4];   // [n], B matrix base +65536 baked in
    #pragma unroll
    for (int n = 0; n < 4; ++n) {
        int rb = wc * 64 + n * 16 + l15;
        unsigned pb = (unsigned)((q4 + (rb >> 1)) & 3);
        offB[n] = 65536u + (unsigned)rb * 64u + pb * 16u;
    }

    // Staging: thread t covers granules G0=t, G1=512+t of each 1024-granule region.
    const int r0g = t >> 2,        p0g = t & 3;
    const int r1g = (512 + t) >> 2, p1g = t & 3;
    const int s0g = (p0g - (r0g >> 1)) & 3;
    const int s1g = (p1g - (r1g >> 1)) & 3;
    const unsigned short* arow0 = A + (size_t)(m0 + r0g) * K_TOT + s0g * 8;
    const unsigned short* arow1 = A + (size_t)(m0 + r1g) * K_TOT + s1g * 8;
    const unsigned short* brow0 = B + (size_t)(n0 + r0g) * K_TOT + s0g * 8;
    const unsigned short* brow1 = B + (size_t)(n0 + r1g) * K_TOT + s1g * 8;
    const unsigned lo0 = (unsigned)t * 16u;
    const unsigned lo1 = lo0 + 8192u;

// Region base: MAT(A=0,B=65536) + BB*32768 + KK*16384.
#define STAGE(ROW0, ROW1, MATOFF, KK, TT, BB) do {                                   \
      const unsigned _base = (MATOFF) + (unsigned)(BB) * 32768u + (KK) * 16384u;     \
      const int _ko = (TT) * 64 + (KK) * 32;                                         \
      __builtin_amdgcn_global_load_lds((gas1)(ROW0 + _ko), (las3)(lds + _base + lo0), 16, 0, 0); \
      __builtin_amdgcn_global_load_lds((gas1)(ROW1 + _ko), (las3)(lds + _base + lo1), 16, 0, 0); \
    } while (0)
#define STAGE_A(KK, TT, BB) STAGE(arow0, arow1, 0u, KK, TT, BB)
#define STAGE_B(KK, TT, BB) STAGE(brow0, brow1, 65536u, KK, TT, BB)

#define LOAD_A4(DST, QM, KK, BB) do {                                                \
      _Pragma("unroll")                                                              \
      for (int i = 0; i < 4; ++i)                                                    \
        DST[i] = *(const bf16x8*)(lds + ((BB) * 32768u + (KK) * 16384u)              \
                                  + offA[(QM) * 4 + i]);                             \
    } while (0)

#define LOAD_B4(DST, KK, BB) do {                                                    \
      _Pragma("unroll")                                                              \
      for (int n = 0; n < 4; ++n)                                                    \
        DST[n] = *(const bf16x8*)(lds + ((BB) * 32768u + (KK) * 16384u) + offB[n]);  \
    } while (0)

#define MFMA16(QM, AF, BG) do {                                                      \
      _Pragma("unroll")                                                              \
      for (int i = 0; i < 4; ++i)                                                    \
        _Pragma("unroll")                                                            \
        for (int n = 0; n < 4; ++n)                                                  \
          acc[(QM) * 4 + i][n] = __builtin_amdgcn_mfma_f32_16x16x32_bf16(            \
              AF[i], BG[n], acc[(QM) * 4 + i][n], 0, 0, 0);                          \
    } while (0)

// One K-tile = 4 phases, ONE barrier each. All reads under prior MFMA:
//  ph1 MFMA(af0,bgA) [preloaded ph4(u-1)]; post: af1(kk0).
//  ph2 MFMA(af1,bgA); post: bgB, af0(kk1).
//  ph3 MFMA(af0,bgB); post: af1(kk1); vmcnt(8) publishes u+1 kk0 regions.
//  ph4 MFMA(af1,bgB); post: bgA(u+1), af0-q0(u+1) from buf^1; vmcnt(6).
#define KTILE(U, BB) do {                                                            \
      const int tt1 = ((U) + 1 < NTILE) ? (U) + 1 : (U) - 1;                         \
      const int tt2 = ((U) + 2 < NTILE) ? (U) + 2 : (U);                             \
      /* phase 1: kk=0 qm=0 */                                                       \
      STAGE_A(1, tt1, 1 - (BB));                                                     \
      __builtin_amdgcn_s_setprio(1); MFMA16(0, af0, bgA);                            \
      __builtin_amdgcn_s_setprio(0);                                                 \
      LOAD_A4(af1, 1, 0, BB);                                                        \
      BAR(); SCHEDB();                                                               \
      /* phase 2: kk=0 qm=1 */                                                       \
      STAGE_B(0, tt2, BB);                                                           \
      __builtin_amdgcn_s_setprio(1); MFMA16(1, af1, bgA);                            \
      __builtin_amdgcn_s_setprio(0);                                                 \
      LOAD_B4(bgB, 1, BB); LOAD_A4(af0, 0, 1, BB);                                   \
      BAR(); SCHEDB();                                                               \
      /* phase 3: kk=1 qm=0 */                                                       \
      STAGE_A(0, tt2, BB);                                                           \
      __builtin_amdgcn_s_setprio(1); MFMA16(0, af0, bgB);                            \
      __builtin_amdgcn_s_setprio(0);                                                 \
      LOAD_A4(af1, 1, 1, BB);                                                        \
      WAITVM8(); SCHEDB(); BAR(); SCHEDB();                                          \
      /* phase 4: kk=1 qm=1 */                                                       \
      STAGE_B(1, tt2, BB);                                                           \
      __builtin_amdgcn_s_setprio(1); MFMA16(1, af1, bgB);                            \
      __builtin_amdgcn_s_setprio(0);                                                 \
      LOAD_B4(bgA, 0, 1 - (BB)); LOAD_A4(af0, 0, 0, 1 - (BB));                       \
      WAITVM6(); SCHEDB(); BAR(); SCHEDB();                                          \
    } while (0)

    f32x4 acc[8][4];
    #pragma unroll
    for (int i = 0; i < 8; ++i)
        #pragma unroll
        for (int j = 0; j < 4; ++j)
            acc[i][j] = (f32x4)0.0f;
    bf16x8 af0[4], af1[4], bgA[4], bgB[4];

    // Prologue: tile0 {Ak0,Bk0,Ak1,Bk1}->buf0, tile1 {Ak0,Bk0,Bk1}->buf1;
    // 14 issued, need first 8 (tile 0) -> vmcnt(6). Then preload ph1(0) frags.
    STAGE_A(0, 0, 0); STAGE_B(0, 0, 0); STAGE_A(1, 0, 0); STAGE_B(1, 0, 0);
    STAGE_A(0, 1, 1); STAGE_B(0, 1, 1); STAGE_B(1, 1, 1);
    WAITVM6(); SCHEDB();
    BAR(); SCHEDB();
    LOAD_B4(bgA, 0, 0); LOAD_A4(af0, 0, 0, 0);

    #pragma unroll 1
    for (int u = 0; u < NTILE; u += 2) {
        KTILE(u, 0);
        KTILE(u + 1, 1);
    }
    WAITVM0();   // drain tail reloads; LDS now dead for staging
    BAR();       // all waves done with main-loop LDS reads

    // ---- Epilogue: LDS-transposed coalesced C-write ----
    // Per half h (rows h*128..h*128+127): waves with wr==h write acc+bias to
    // f32 LDS [128][EPI_STRIDE]; then all 512 threads store dwordx4.
    float* ldsF = (float*)lds;
    #pragma unroll 1
    for (int h = 0; h < 2; ++h) {
        if (wr == h) {
            #pragma unroll
            for (int j = 0; j < 4; ++j) {
                int n = n0 + wc * 64 + j * 16 + l15;
                float bv = bias[n];
                #pragma unroll
                for (int i = 0; i < 8; ++i) {
                    int lr = i * 16 + (q4 << 2);   // local row base 0..124
                    #pragma unroll
                    for (int r = 0; r < 4; ++r)
                        ldsF[(lr + r) * EPI_STRIDE + wc * 64 + j * 16 + l15] =
                            acc[i][j][r] + bv;
                }
            }
        }
        BAR();
        // 128 rows x 64 float4 = 8192 float4; 512 threads x 16 iters.
        #pragma unroll
        for (int it = 0; it < 16; ++it) {
            int idx2 = it * 512 + t;
            int row = idx2 >> 6;
            int c4 = idx2 & 63;
            float4 v = *(const float4*)&ldsF[row * EPI_STRIDE + c4 * 4];
            *(float4*)&C[(size_t)(m0 + h * 128 + row) * N_TOT + n0 + c4 * 4] = v;
        }
        BAR();   // before next half overwrites LDS
    }
}

extern "C" void kernel_launch(void* const* d_in, const int* in_sizes, int n_in,
                              void* d_out, int out_size, void* d_ws, size_t ws_size,
                              hipStream_t stream) {
    const float* x    = (const float*)d_in[0];
    const float* w    = (const float*)d_in[1];
    const float* bias = (const float*)d_in[2];
    float* out = (float*)d_out;

    unsigned short* wb = (unsigned short*)d_ws;                      // 32 MiB
    unsigned short* xb = wb + (size_t)N_TOT * K_TOT;                 // +64 MiB

    prep_kernel<<<4096, 256, 0, stream>>>(w, wb, x, xb);

    hipFuncSetAttribute(reinterpret_cast<const void*>(gemm_kernel),
                        hipFuncAttributeMaxDynamicSharedMemorySize, 135168);
    gemm_kernel<<<512, 512, 135168, stream>>>(xb, wb, bias, out);
}